// Round 11
// baseline (289.059 us; speedup 1.0000x reference)
//
#include <hip/hip_runtime.h>
#include <hip/hip_cooperative_groups.h>
#include <math.h>

namespace cg = cooperative_groups;

#define BB 8
#define HWH (512*512)
#define NID 15
#define NSEG (BB*NID)
#define NBINS 256
#define AAF ((float)NBINS/13.0f)
#define LOG2E 1.442695041f
#define LN2 0.6931471806f
#define NBLK 512
#define NTHR 512
#define SLICES 128

typedef unsigned int uint32;
typedef unsigned long long uint64;

__device__ __forceinline__ float ftanh(float x){
    float t = __expf(2.0f*x);
    return 1.0f - 2.0f*__builtin_amdgcn_rcpf(t + 1.0f);
}
__device__ __forceinline__ float fsigmoid(float x){
    return __builtin_amdgcn_rcpf(1.0f + __expf(-x));
}
__device__ __forceinline__ float sconst(float x){
    return __uint_as_float(__builtin_amdgcn_readfirstlane(__float_as_uint(x)));
}

// ==================== cooperative mega-kernel ====================
__global__ __launch_bounds__(512, 4) void mega(
        const float* __restrict__ pred, const int* __restrict__ labels,
        const int* __restrict__ inst,
        uint64* __restrict__ pstat64, float* __restrict__ pstatf,
        float* __restrict__ pstatf2,
        float* __restrict__ focal_p, float* __restrict__ bgseed_p,
        float* __restrict__ stats, float* __restrict__ derived,
        float* __restrict__ results,
        float* __restrict__ focalR, float* __restrict__ bgseedR,
        uint32* __restrict__ Hc, uint32* __restrict__ Hg,
        float* __restrict__ part2f, float* __restrict__ out){
    cg::grid_group grid = cg::this_grid();
    int blk = blockIdx.x;
    int b = blk & 7;                 // XCD affinity
    int sp = blk >> 3;               // 64 slices per image
    int t = threadIdx.x;
    int lane = t & 63;
    int w = t >> 6;

    __shared__ uint64 s64[NID];
    __shared__ float ssig[NID], ssig2[NID];
    __shared__ float wfb[8][2];
    __shared__ __align__(16) uint32 hist[NID*NBINS];
    __shared__ float ssl[NID], vsB[NID];
    __shared__ uint32 wbc[8], wbg[8], wexc[8], wexg[8];
    __shared__ float wsum[8];
    __shared__ float red8[8];
    __shared__ float perb[BB];

    if (t < NID){ s64[t] = 0ull; ssig[t] = 0.0f; ssig2[t] = 0.0f; }
    {   // zero final histograms (Hc,Hg contiguous) + seed partials
        const int stripe = 2*NSEG*NBINS/NBLK;     // 120
        for (int i = t; i < stripe; i += NTHR) Hc[blk*stripe + i] = 0u;
        if (blk == 0 && t < NSEG) part2f[t] = 0.0f;
    }
    __syncthreads();

    const int Q = HWH/4;
    const float* pb = pred + (size_t)b*6*HWH;
    const float4* P0 = (const float4*)pb;
    const float4* P1 = P0 + Q;
    const float4* P2 = P0 + 2*Q;
    const float4* P3 = P0 + 3*Q;
    const float4* P4 = P0 + 4*Q;
    const float4* P5 = P0 + 5*Q;
    const int4* Lp = (const int4*)(labels + (size_t)b*3*HWH);
    const int4* I  = (const int4*)(inst + (size_t)b*HWH);
    const float SC = 2.0f/511.0f;
    int qbase = sp*1024;

    // -------- Part A: stats/focal/bgseed; hold ch0/ch1/inst/seed in regs --------
    float4 ra0, ra1, rc0, rc1, rs0, rs1;
    int4 ri0, ri1;
    float facc = 0.0f, bacc = 0.0f;
    #pragma unroll
    for (int it = 0; it < 2; ++it){
        int q = qbase + it*512 + t;
        float4 a = P0[q], c = P1[q];
        float4 sg4 = P2[q], z3 = P3[q], z4 = P4[q], z5 = P5[q];
        int4 id4 = I[q];
        int4 l0 = Lp[q], l1 = Lp[Q+q], l2 = Lp[2*Q+q];
        int p = q*4;
        int w0 = p & 511, h0 = p >> 9;
        auto px = [&](float sgv, float z3v, float z4v, float z5v, int id,
                      int A0, int A1, int A2, int wv) -> float {
            float seed = fsigmoid(z5v);
            if (A2 == 0) bacc += seed*seed;
            int tc = 0, best = A0;
            if (A1 > best){ tc = 1; best = A1; }
            if (A2 > best){ tc = 2; }
            float m = fmaxf(z3v, fmaxf(z4v, z5v));
            float e3 = __expf(z3v-m), e4 = __expf(z4v-m), e5 = __expf(z5v-m);
            float sum = e3+e4+e5;
            float lse = m + __logf(sum);
            float zt = (tc==0) ? z3v : ((tc==1) ? z4v : z5v);
            float et = (tc==0) ? e3  : ((tc==1) ? e4  : e5);
            float lp = zt - lse;
            float pt = et*__builtin_amdgcn_rcpf(sum);
            float om = 1.0f - pt;
            facc -= om*om*lp;
            if (id > 0){
                atomicAdd(&s64[id-1],
                          (1ull<<42) | ((uint64)(uint32)wv<<21) | (uint64)(uint32)h0);
                atomicAdd(&ssig[id-1], sgv);
                atomicAdd(&ssig2[id-1], sgv*sgv);
            }
            return seed;
        };
        float4 seed4;
        seed4.x = px(sg4.x, z3.x, z4.x, z5.x, id4.x, l0.x, l1.x, l2.x, w0);
        seed4.y = px(sg4.y, z3.y, z4.y, z5.y, id4.y, l0.y, l1.y, l2.y, w0+1);
        seed4.z = px(sg4.z, z3.z, z4.z, z5.z, id4.z, l0.z, l1.z, l2.z, w0+2);
        seed4.w = px(sg4.w, z3.w, z4.w, z5.w, id4.w, l0.w, l1.w, l2.w, w0+3);
        if (it == 0){ ra0 = a; rc0 = c; ri0 = id4; rs0 = seed4; }
        else        { ra1 = a; rc1 = c; ri1 = id4; rs1 = seed4; }
    }
    for (int o = 32; o; o >>= 1){
        facc += __shfl_xor(facc, o);
        bacc += __shfl_xor(bacc, o);
    }
    if (lane == 0){ wfb[w][0] = facc; wfb[w][1] = bacc; }
    __syncthreads();
    if (t < NID){
        pstat64[blk*16 + t] = s64[t];
        pstatf [blk*16 + t] = ssig[t];
        pstatf2[blk*16 + t] = ssig2[t];
    }
    if (t == 0){
        float f = 0.0f, g = 0.0f;
        for (int i = 0; i < 8; i++){ f += wfb[i][0]; g += wfb[i][1]; }
        focal_p[blk] = f; bgseed_p[blk] = g;
    }

    grid.sync();

    // -------- Part B: reduce partials -> stats/derived/var; focal/bgseed --------
    if (blk < NSEG){
        int bb = blk & 7, k = blk >> 3;
        if (t < 64){
            uint64 v = pstat64[(size_t)(bb + 8*t)*16 + k];
            float acnt = (float)(uint32)(v >> 42);
            float asw  = (float)(uint32)((v >> 21) & 0x1FFFFF);
            float ash  = (float)(uint32)(v & 0x1FFFFF);
            float af   = pstatf [(bb + 8*t)*16 + k];
            float af2  = pstatf2[(bb + 8*t)*16 + k];
            for (int o = 32; o; o >>= 1){
                acnt += __shfl_xor(acnt, o);
                asw  += __shfl_xor(asw,  o);
                ash  += __shfl_xor(ash,  o);
                af   += __shfl_xor(af,   o);
                af2  += __shfl_xor(af2,  o);
            }
            if (lane == 0){
                float cnt = acnt;
                float safe = fmaxf(cnt, 1.0f);
                float inv = 1.0f/safe;
                int seg = bb*NID + k;
                derived[seg*4+0] = asw*SC*inv;
                derived[seg*4+1] = ash*SC*inv;
                float sm = af*inv;
                derived[seg*4+2] = __expf(10.0f*sm);
                derived[seg*4+3] = sm;
                stats[bb*60 + k*4] = cnt;
                results[(size_t)seg*3 + 1] = af2 - cnt*sm*sm;
            }
        }
    } else if (blk == NSEG){
        if (t < 8) red8[t] = 0.0f;
        __syncthreads();
        atomicAdd(&red8[t & 7], bgseed_p[t]);
        float f = focal_p[t];
        for (int o = 32; o; o >>= 1) f += __shfl_xor(f, o);
        if (lane == 0) wsum[w] = f;
        __syncthreads();
        if (t < 8) bgseedR[t] = red8[t];
        if (t == 0){
            float fs = 0.0f;
            for (int i = 0; i < 8; i++) fs += wsum[i];
            focalR[0] = fs;
        }
    }

    grid.sync();

    // -------- Part C: 15-id histogram on register-held pixels --------
    {
        uint4* hz = (uint4*)hist;
        for (int i = t; i < NID*NBINS/4; i += NTHR) hz[i] = make_uint4(0,0,0,0);
    }
    if (t < NID){
        ssl[t] = derived[(size_t)(b*NID + t)*4 + 2];
        vsB[t] = 0.0f;
    }
    float kcx[NID], kcy[NID], kcs[NID];
    #pragma unroll
    for (int j = 0; j < NID; j++){
        const float* d0 = derived + (size_t)(b*NID + j)*4;
        kcx[j] = sconst(d0[0]);
        kcy[j] = sconst(d0[1]);
        kcs[j] = sconst(LOG2E*AAF*d0[2]);
    }
    __syncthreads();

    auto pc = [&](float av, float cv, int id, float gxv, float gy, float seed){
        float ex = ftanh(av) + gxv;
        float ey = ftanh(cv) + gy;
        int own = id - 1;
        float r2own = 0.0f;
        #pragma unroll
        for (int j = 0; j < NID; j++){
            float dx = ex - kcx[j], dy = ey - kcy[j];
            float r2 = fmaf(dx, dx, dy*dy);
            if (j == own) r2own = r2;
            float binf = fmaf(-kcs[j], r2, (float)NBINS);
            binf = fminf(fmaxf(binf, 0.0f), (float)(NBINS-1));
            int bin = (int)binf;
            bool isown = (j == own);
            bool hot = (bin == 0) && !isown;
            uint64 bal = __ballot(hot);
            if (hot){
                if ((bal & ((1ull << lane) - 1ull)) == 0ull)
                    atomicAdd(&hist[j*NBINS], ((uint32)__popcll(bal)) << 16);
            } else if (!isown){
                atomicAdd(&hist[j*NBINS + bin], 65536u);
            }
        }
        if (own >= 0){
            float d = __expf(-ssl[own]*r2own);
            float e = fmaf(-2.0f, d, 2.0f);
            float bf = fmaf(__log2f(e), AAF, (float)NBINS - AAF);
            bf = fminf(fmaxf(bf, 0.0f), (float)(NBINS-1));
            atomicAdd(&hist[own*NBINS + (int)bf], 65537u);
            float sd = seed - d;
            atomicAdd(&vsB[own], sd*sd);
        }
    };
    {
        int q0 = qbase + t, q1 = qbase + 512 + t;
        int p0 = q0*4, p1 = q1*4;
        float gx0 = (float)(p0 & 511)*SC, gy0 = (float)(p0 >> 9)*SC;
        float gx1 = (float)(p1 & 511)*SC, gy1 = (float)(p1 >> 9)*SC;
        pc(ra0.x, rc0.x, ri0.x, gx0,        gy0, rs0.x);
        pc(ra0.y, rc0.y, ri0.y, gx0+SC,     gy0, rs0.y);
        pc(ra0.z, rc0.z, ri0.z, gx0+2*SC,   gy0, rs0.z);
        pc(ra0.w, rc0.w, ri0.w, gx0+3*SC,   gy0, rs0.w);
        pc(ra1.x, rc1.x, ri1.x, gx1,        gy1, rs1.x);
        pc(ra1.y, rc1.y, ri1.y, gx1+SC,     gy1, rs1.y);
        pc(ra1.z, rc1.z, ri1.z, gx1+2*SC,   gy1, rs1.z);
        pc(ra1.w, rc1.w, ri1.w, gx1+3*SC,   gy1, rs1.w);
    }
    __syncthreads();
    {
        size_t hbase = (size_t)b*NID*NBINS;
        for (int i = t; i < NID*NBINS; i += NTHR){
            uint32 v = hist[i];
            if (v){
                uint32 cc = v >> 16, gg = v & 0xFFFFu;
                if (cc) atomicAdd(&Hc[hbase + i], cc);
                if (gg) atomicAdd(&Hg[hbase + i], gg);
            }
        }
        if (t < NID && vsB[t] != 0.0f)
            atomicAdd(&part2f[b*NID + t], vsB[t]);
    }

    grid.sync();

    // -------- Part D: descending Lovasz scan --------
    if (blk < NSEG){
        int bb = blk & 7, k = blk >> 3;
        int seg = bb*NID + k;
        uint32 cd = 0, gd = 0;
        if (t < 256){
            size_t base = (size_t)seg*NBINS;
            cd = Hc[base + NBINS-1-t];
            gd = Hg[base + NBINS-1-t];
        }
        uint32 ci = cd, gi2 = gd;
        for (int o = 1; o < 64; o <<= 1){
            uint32 cu = __shfl_up(ci, o);
            uint32 gu = __shfl_up(gi2, o);
            if (lane >= o){ ci += cu; gi2 += gu; }
        }
        if (lane == 63){ wbc[w] = ci; wbg[w] = gi2; }
        __syncthreads();
        if (t == 0){
            uint32 rc2 = 0, rg2 = 0;
            for (int i = 0; i < 4; i++){
                uint32 aa = wbc[i], bq = wbg[i];
                wexc[i] = rc2; wexg[i] = rg2;
                rc2 += aa; rg2 += bq;
            }
        }
        __syncthreads();
        float G = stats[bb*60 + k*4];
        float contrib = 0.0f;
        if (t < 256 && G > 0.0f && (cd | gd)){
            uint32 nb = wexc[w] + (ci - cd);
            uint32 gb = wexg[w] + (gi2 - gd);
            float jp = 0.0f;
            if (nb > 0) jp = 1.0f - (G - (float)gb)/(G + (float)(nb - gb));
            uint32 n = nb + cd, gg = gb + gd;
            float j2 = 1.0f - (G - (float)gg)/(G + (float)(n - gg));
            int bin = NBINS-1-t;
            float ev = __expf(LN2*(((float)bin + 0.5f)*(13.0f/(float)NBINS) - 12.0f));
            contrib = ev*(j2 - jp);
        }
        for (int o = 32; o; o >>= 1) contrib += __shfl_xor(contrib, o);
        if (lane == 0) wsum[w] = contrib;
        __syncthreads();
        if (t == 0){
            results[(size_t)seg*3 + 0] = wsum[0]+wsum[1]+wsum[2]+wsum[3];
            results[(size_t)seg*3 + 2] = part2f[seg];
        }
    }

    grid.sync();

    // -------- Part E: final combine --------
    if (blk == 0){
        if (t < BB){
            float nvalid = 0.0f, lsum = 0.0f, vsum = 0.0f, ssum = 0.0f;
            for (int k = 0; k < NID; k++){
                int seg = t*NID + k;
                float cnt = stats[t*60 + k*4];
                if (cnt > 0.0f){
                    nvalid += 1.0f;
                    lsum += results[seg*3+0];
                    vsum += results[seg*3+1]/cnt;
                    ssum += results[seg*3+2];
                }
            }
            float nobj = fmaxf(nvalid, 1.0f);
            perb[t] = lsum/nobj + 10.0f*(vsum/nobj) + (bgseedR[t] + ssum)/(float)HWH;
        }
        __syncthreads();
        if (t == 0){
            float s = 0.0f;
            for (int bq = 0; bq < BB; bq++) s += perb[bq];
            out[0] = s/(float)BB + focalR[0]/(float)(BB*HWH);
        }
    }
}

// ==================== fallback: R10 5-kernel pipeline ====================
__global__ __launch_bounds__(256, 8) void phase1f(const float* __restrict__ pred,
        const int* __restrict__ labels, const int* __restrict__ inst,
        uint64* __restrict__ pstat64, float* __restrict__ pstatf,
        float* __restrict__ pstatf2,
        float* __restrict__ bgseed_p, float* __restrict__ focal_p){
    int blk = blockIdx.x;
    int b = blk >> 8;
    int t = threadIdx.x;
    int q = (blk & 255)*256 + t;

    __shared__ uint64 s64[NID];
    __shared__ float ssig[NID], ssig2[NID];
    __shared__ float wfb[4][2];
    if (t < NID){ s64[t] = 0ull; ssig[t] = 0.0f; ssig2[t] = 0.0f; }
    __syncthreads();

    const int Q = HWH/4;
    const float4* P = (const float4*)(pred + (size_t)b*6*HWH);
    const int4* L = (const int4*)(labels + (size_t)b*3*HWH);
    const int4* I = (const int4*)(inst + (size_t)b*HWH);
    float4 sg4 = P[2*Q+q], z3 = P[3*Q+q], z4 = P[4*Q+q], z5 = P[5*Q+q];
    int4 id4 = I[q];
    int4 l0 = L[q], l1 = L[Q+q], l2 = L[2*Q+q];
    int p = q*4;
    int w0 = p & 511, h0 = p >> 9;

    float facc = 0.0f, bacc = 0.0f;
    auto px = [&](float sgv, float z3v, float z4v, float z5v, int id,
                  int L0, int L1, int L2, int wv){
        float seed = fsigmoid(z5v);
        if (L2 == 0) bacc += seed*seed;
        int tc = 0, best = L0;
        if (L1 > best){ tc = 1; best = L1; }
        if (L2 > best){ tc = 2; }
        float m = fmaxf(z3v, fmaxf(z4v, z5v));
        float e3 = __expf(z3v-m), e4 = __expf(z4v-m), e5 = __expf(z5v-m);
        float sum = e3+e4+e5;
        float lse = m + __logf(sum);
        float zt = (tc==0) ? z3v : ((tc==1) ? z4v : z5v);
        float et = (tc==0) ? e3  : ((tc==1) ? e4  : e5);
        float lp = zt - lse;
        float pt = et*__builtin_amdgcn_rcpf(sum);
        float om = 1.0f - pt;
        facc -= om*om*lp;
        if (id > 0){
            atomicAdd(&s64[id-1],
                      (1ull<<42) | ((uint64)(uint32)wv<<21) | (uint64)(uint32)h0);
            atomicAdd(&ssig[id-1], sgv);
            atomicAdd(&ssig2[id-1], sgv*sgv);
        }
    };
    px(sg4.x, z3.x, z4.x, z5.x, id4.x, l0.x, l1.x, l2.x, w0);
    px(sg4.y, z3.y, z4.y, z5.y, id4.y, l0.y, l1.y, l2.y, w0+1);
    px(sg4.z, z3.z, z4.z, z5.z, id4.z, l0.z, l1.z, l2.z, w0+2);
    px(sg4.w, z3.w, z4.w, z5.w, id4.w, l0.w, l1.w, l2.w, w0+3);

    for (int o = 32; o; o >>= 1){
        facc += __shfl_xor(facc, o);
        bacc += __shfl_xor(bacc, o);
    }
    if ((t & 63) == 0){ wfb[t>>6][0] = facc; wfb[t>>6][1] = bacc; }
    __syncthreads();
    if (t < NID){
        pstat64[blk*16 + t] = s64[t];
        pstatf [blk*16 + t] = ssig[t];
        pstatf2[blk*16 + t] = ssig2[t];
    }
    if (t == 0){
        focal_p[blk]  = wfb[0][0]+wfb[1][0]+wfb[2][0]+wfb[3][0];
        bgseed_p[blk] = wfb[0][1]+wfb[1][1]+wfb[2][1]+wfb[3][1];
    }
}

__global__ __launch_bounds__(512) void phaseR(const uint64* __restrict__ pstat64,
        const float* __restrict__ pstatf, const float* __restrict__ pstatf2,
        const float* __restrict__ focal_p, const float* __restrict__ bgseed_p,
        float* __restrict__ stats, float* __restrict__ derived,
        float* __restrict__ results,
        float* __restrict__ focalR, float* __restrict__ bgseedR,
        uint32* __restrict__ Hzero, float* __restrict__ part2f){
    int b = blockIdx.x;
    int t = threadIdx.x;
    {
        const int stripe = 2*NSEG*NBINS/8;
        for (int i = b*stripe + t; i < (b+1)*stripe; i += 512) Hzero[i] = 0u;
        if (b == 0 && t < NSEG) part2f[t] = 0.0f;
    }
    int k = t & 15, chunk = t >> 4;
    float acnt = 0, asw = 0, ash = 0, af = 0, af2 = 0;
    for (int i = 0; i < 8; i++){
        int blk = b*256 + chunk*8 + i;
        uint64 v = pstat64[blk*16 + k];
        acnt += (float)(uint32)(v >> 42);
        asw  += (float)(uint32)((v >> 21) & 0x1FFFFF);
        ash  += (float)(uint32)(v & 0x1FFFFF);
        af   += pstatf[blk*16 + k];
        af2  += pstatf2[blk*16 + k];
    }
    __shared__ float tc[16], tw[16], th[16], ts[16], ts2[16];
    if (t < 16){ tc[t]=0; tw[t]=0; th[t]=0; ts[t]=0; ts2[t]=0; }
    __syncthreads();
    atomicAdd(&tc[k], acnt);
    atomicAdd(&tw[k], asw);
    atomicAdd(&th[k], ash);
    atomicAdd(&ts[k], af);
    atomicAdd(&ts2[k], af2);
    __syncthreads();
    if (t < NID){
        float cnt = tc[t];
        float safe = fmaxf(cnt, 1.0f);
        float inv = 1.0f/safe;
        const float SC = 2.0f/511.0f;
        derived[(b*NID+t)*4+0] = tw[t]*SC*inv;
        derived[(b*NID+t)*4+1] = th[t]*SC*inv;
        float sm = ts[t]*inv;
        derived[(b*NID+t)*4+2] = __expf(10.0f*sm);
        derived[(b*NID+t)*4+3] = sm;
        stats[b*60 + t*4] = cnt;
        results[(size_t)(b*NID+t)*3 + 1] = ts2[t] - cnt*sm*sm;
    }
    int w = t >> 6, lane = t & 63;
    if (w == 0){
        float f = 0;
        for (int j = 0; j < 4; j++) f += focal_p[b*256 + j*64 + lane];
        for (int o = 32; o; o >>= 1) f += __shfl_xor(f, o);
        if (lane == 0) focalR[b] = f;
    } else if (w == 1){
        float g = 0;
        for (int j = 0; j < 4; j++) g += bgseed_p[b*256 + j*64 + lane];
        for (int o = 32; o; o >>= 1) g += __shfl_xor(g, o);
        if (lane == 0) bgseedR[b] = g;
    }
}

__global__ __launch_bounds__(512, 8) void phaseLH(const float* __restrict__ pred,
        const int* __restrict__ inst, const float* __restrict__ derived,
        uint32* __restrict__ Hc, uint32* __restrict__ Hg,
        float* __restrict__ part2f){
    int idx = blockIdx.x;
    int b = idx & 7;
    int sp = idx >> 3;
    int t = threadIdx.x;
    int lane = t & 63;

    __shared__ __align__(16) uint32 hist[NID*NBINS];
    __shared__ float ssl[NID];
    __shared__ float vsB[NID];
    {
        uint4* hz = (uint4*)hist;
        for (int i = t; i < NID*NBINS/4; i += 512) hz[i] = make_uint4(0,0,0,0);
    }
    if (t < NID){
        ssl[t] = derived[(size_t)(b*NID + t)*4 + 2];
        vsB[t] = 0.0f;
    }
    float kcx[NID], kcy[NID], kcs[NID];
    #pragma unroll
    for (int j = 0; j < NID; j++){
        const float* d0 = derived + (size_t)(b*NID + j)*4;
        kcx[j] = sconst(d0[0]);
        kcy[j] = sconst(d0[1]);
        kcs[j] = sconst(LOG2E*AAF*d0[2]);
    }
    __syncthreads();

    const int Q = HWH/4;
    const int qps = Q / SLICES;
    int q0 = sp * qps;
    const float* pb = pred + (size_t)b*6*HWH;
    const float4* P0 = (const float4*)pb;
    const float4* P1 = P0 + Q;
    const float* z5p = pb + 5*HWH;
    const int4* I = (const int4*)(inst + (size_t)b*HWH);
    const float SC = 2.0f/511.0f;

    for (int q = q0 + t; q < q0 + qps; q += 512){
        int4 id4 = I[q];
        float4 a = P0[q], c = P1[q];
        int p = q*4;
        float gx = (float)(p & 511)*SC;
        float gy = (float)(p >> 9)*SC;
        auto px = [&](float av, float cv, int id, float gxv, int pi){
            float ex = ftanh(av) + gxv;
            float ey = ftanh(cv) + gy;
            int own = id - 1;
            float r2own = 0.0f;
            #pragma unroll
            for (int j = 0; j < NID; j++){
                float dx = ex - kcx[j], dy = ey - kcy[j];
                float r2 = fmaf(dx, dx, dy*dy);
                if (j == own) r2own = r2;
                float binf = fmaf(-kcs[j], r2, (float)NBINS);
                binf = fminf(fmaxf(binf, 0.0f), (float)(NBINS-1));
                int bin = (int)binf;
                bool isown = (j == own);
                bool hot = (bin == 0) && !isown;
                uint64 bal = __ballot(hot);
                if (hot){
                    if ((bal & ((1ull << lane) - 1ull)) == 0ull)
                        atomicAdd(&hist[j*NBINS],
                                  ((uint32)__popcll(bal)) << 16);
                } else if (!isown){
                    atomicAdd(&hist[j*NBINS + bin], 65536u);
                }
            }
            if (own >= 0){
                float d = __expf(-ssl[own]*r2own);
                float e = fmaf(-2.0f, d, 2.0f);
                float bf = fmaf(__log2f(e), AAF, (float)NBINS - AAF);
                bf = fminf(fmaxf(bf, 0.0f), (float)(NBINS-1));
                atomicAdd(&hist[own*NBINS + (int)bf], 65537u);
                float seed = fsigmoid(z5p[pi]);
                float sd = seed - d;
                atomicAdd(&vsB[own], sd*sd);
            }
        };
        px(a.x, c.x, id4.x, gx,      p);
        px(a.y, c.y, id4.y, gx+SC,   p+1);
        px(a.z, c.z, id4.z, gx+2*SC, p+2);
        px(a.w, c.w, id4.w, gx+3*SC, p+3);
    }
    __syncthreads();
    size_t base = (size_t)b*NID*NBINS;
    for (int i = t; i < NID*NBINS; i += 512){
        uint32 v = hist[i];
        if (v){
            uint32 cc = v >> 16, gg = v & 0xFFFFu;
            if (cc) atomicAdd(&Hc[base + i], cc);
            if (gg) atomicAdd(&Hg[base + i], gg);
        }
    }
    if (t < NID && vsB[t] != 0.0f)
        atomicAdd(&part2f[b*NID + t], vsB[t]);
}

__global__ __launch_bounds__(256) void phaseLS(const uint32* __restrict__ Hc,
        const uint32* __restrict__ Hg, const float* __restrict__ part2f,
        const float* __restrict__ stats, float* __restrict__ results){
    int idx = blockIdx.x;
    int b = idx & 7, k = idx >> 3;
    int seg = b*NID + k;
    int t = threadIdx.x;

    __shared__ uint32 wbc[4], wbg[4], wexc[4], wexg[4];
    __shared__ float wsum[4];

    size_t base = (size_t)seg*NBINS;
    uint32 cd = Hc[base + NBINS-1-t];
    uint32 gd = Hg[base + NBINS-1-t];
    uint32 ci = cd, gi2 = gd;
    int lane = t & 63, w = t >> 6;
    for (int o = 1; o < 64; o <<= 1){
        uint32 cu = __shfl_up(ci, o);
        uint32 gu = __shfl_up(gi2, o);
        if (lane >= o){ ci += cu; gi2 += gu; }
    }
    if (lane == 63){ wbc[w] = ci; wbg[w] = gi2; }
    __syncthreads();
    if (t == 0){
        uint32 rc = 0, rg = 0;
        for (int i = 0; i < 4; i++){
            uint32 a = wbc[i], bq = wbg[i];
            wexc[i] = rc; wexg[i] = rg;
            rc += a; rg += bq;
        }
    }
    __syncthreads();

    float G = stats[b*60 + k*4];
    float contrib = 0.0f;
    if (G > 0.0f && (cd | gd)){
        uint32 nb = wexc[w] + (ci - cd);
        uint32 gb = wexg[w] + (gi2 - gd);
        float jp = 0.0f;
        if (nb > 0) jp = 1.0f - (G - (float)gb)/(G + (float)(nb - gb));
        uint32 n = nb + cd, gg = gb + gd;
        float j2 = 1.0f - (G - (float)gg)/(G + (float)(n - gg));
        int bin = NBINS-1-t;
        float ev = __expf(LN2*(((float)bin + 0.5f)*(13.0f/(float)NBINS) - 12.0f));
        contrib = ev*(j2 - jp);
    }
    for (int o = 32; o; o >>= 1) contrib += __shfl_xor(contrib, o);
    if ((t & 63) == 0) wsum[w] = contrib;
    __syncthreads();
    if (t == 0){
        results[(size_t)seg*3 + 0] = wsum[0]+wsum[1]+wsum[2]+wsum[3];
        results[(size_t)seg*3 + 2] = part2f[seg];
    }
}

__global__ void phase5(const float* __restrict__ stats, const float* __restrict__ results,
                       const float* __restrict__ bgseedR, const float* __restrict__ focalR,
                       float* __restrict__ out){
    int t = threadIdx.x;
    __shared__ float per_b[BB];
    if (t < BB){
        float nvalid = 0.0f, lsum = 0.0f, vsum = 0.0f, ssum = 0.0f;
        for (int k = 0; k < NID; k++){
            int seg = t*NID + k;
            float cnt = stats[t*60 + k*4];
            if (cnt > 0.0f){
                nvalid += 1.0f;
                lsum += results[seg*3+0];
                vsum += results[seg*3+1]/cnt;
                ssum += results[seg*3+2];
            }
        }
        float nobj = fmaxf(nvalid, 1.0f);
        per_b[t] = lsum/nobj + 10.0f*(vsum/nobj) + (bgseedR[t] + ssum)/(float)HWH;
    }
    __syncthreads();
    if (t == 0){
        float s = 0.0f, fs = 0.0f;
        for (int b = 0; b < BB; b++){ s += per_b[b]; fs += focalR[b]; }
        out[0] = s/(float)BB + fs/(float)(BB*HWH);
    }
}

extern "C" void kernel_launch(void* const* d_in, const int* in_sizes, int n_in,
                              void* d_out, int out_size, void* d_ws, size_t ws_size,
                              hipStream_t stream){
    const float* pred  = (const float*)d_in[0];
    const int*   labels= (const int*)d_in[1];
    const int*   inst  = (const int*)d_in[2];
    float* out = (float*)d_out;

    // layout sized for the larger (fallback) pipeline; mega uses a prefix of it
    uint32* Hc     = (uint32*)d_ws;                          // NSEG*NBINS
    uint32* Hg     = Hc + (size_t)NSEG*NBINS;                // NSEG*NBINS
    float* part2f  = (float*)(Hg + (size_t)NSEG*NBINS);      // NSEG (pad to 128)
    uint64* pstat64= (uint64*)(part2f + 128);                // 2048*16
    float* pstatf  = (float*)(pstat64 + 2048*16);
    float* pstatf2 = pstatf + 2048*16;
    float* focal_p = pstatf2 + 2048*16;
    float* bgseed_p= focal_p + 2048;
    float* stats   = bgseed_p + 2048;
    float* derived = stats + 480;
    float* results = derived + 480;
    float* focalR  = results + 360;
    float* bgseedR = focalR + 8;

    void* args[] = { (void*)&pred, (void*)&labels, (void*)&inst,
                     (void*)&pstat64, (void*)&pstatf, (void*)&pstatf2,
                     (void*)&focal_p, (void*)&bgseed_p,
                     (void*)&stats, (void*)&derived, (void*)&results,
                     (void*)&focalR, (void*)&bgseedR,
                     (void*)&Hc, (void*)&Hg, (void*)&part2f, (void*)&out };
    hipError_t err = hipLaunchCooperativeKernel((void*)mega, dim3(NBLK), dim3(NTHR),
                                                args, 0, stream);
    if (err != hipSuccess){
        // fallback: proven 5-kernel pipeline
        hipLaunchKernelGGL(phase1f, dim3(2048), dim3(256), 0, stream,
                           pred, labels, inst, pstat64, pstatf, pstatf2,
                           bgseed_p, focal_p);
        hipLaunchKernelGGL(phaseR, dim3(8), dim3(512), 0, stream,
                           pstat64, pstatf, pstatf2, focal_p, bgseed_p,
                           stats, derived, results, focalR, bgseedR, Hc, part2f);
        hipLaunchKernelGGL(phaseLH, dim3(BB*SLICES), dim3(512), 0, stream,
                           pred, inst, derived, Hc, Hg, part2f);
        hipLaunchKernelGGL(phaseLS, dim3(NSEG), dim3(256), 0, stream,
                           Hc, Hg, part2f, stats, results);
        hipLaunchKernelGGL(phase5, dim3(1), dim3(64), 0, stream,
                           stats, results, bgseedR, focalR, out);
    }
}

// Round 13
// 78.228 us; speedup vs baseline: 3.6951x; 3.6951x over previous
//
#include <hip/hip_runtime.h>
#include <math.h>

#define BB 8
#define HWH (512*512)
#define NID 15
#define NSEG (BB*NID)
#define NBINS 256
#define AAF ((float)NBINS/13.0f)
#define LOG2E 1.442695041f
#define LN2 0.6931471806f
#define SLICES 128

typedef unsigned int uint32;
typedef unsigned long long uint64;

__device__ __forceinline__ float ftanh(float x){
    float t = __expf(2.0f*x);
    return 1.0f - 2.0f*__builtin_amdgcn_rcpf(t + 1.0f);
}
__device__ __forceinline__ float fsigmoid(float x){
    return __builtin_amdgcn_rcpf(1.0f + __expf(-x));
}
__device__ __forceinline__ float sconst(float x){
    return __uint_as_float(__builtin_amdgcn_readfirstlane(__float_as_uint(x)));
}

// ---- phase1f: per-chunk id-stats (packed u64 + sigma + sigma^2) + focal/bgseed ----
__global__ __launch_bounds__(256, 8) void phase1f(const float* __restrict__ pred,
        const int* __restrict__ labels, const int* __restrict__ inst,
        uint64* __restrict__ pstat64, float* __restrict__ pstatf,
        float* __restrict__ pstatf2,
        float* __restrict__ bgseed_p, float* __restrict__ focal_p){
    int blk = blockIdx.x;            // 2048 blocks, 256 per image
    int b = blk >> 8;
    int t = threadIdx.x;
    int q = (blk & 255)*256 + t;     // float4 index in image

    __shared__ uint64 s64[NID];
    __shared__ float ssig[NID], ssig2[NID];
    __shared__ float wfb[4][2];
    if (t < NID){ s64[t] = 0ull; ssig[t] = 0.0f; ssig2[t] = 0.0f; }
    __syncthreads();

    const int Q = HWH/4;
    const float4* P = (const float4*)(pred + (size_t)b*6*HWH);
    const int4* L = (const int4*)(labels + (size_t)b*3*HWH);
    const int4* I = (const int4*)(inst + (size_t)b*HWH);
    float4 sg4 = P[2*Q+q], z3 = P[3*Q+q], z4 = P[4*Q+q], z5 = P[5*Q+q];
    int4 id4 = I[q];
    int4 l0 = L[q], l1 = L[Q+q], l2 = L[2*Q+q];
    int p = q*4;
    int w0 = p & 511, h0 = p >> 9;

    float facc = 0.0f, bacc = 0.0f;
    auto px = [&](float sgv, float z3v, float z4v, float z5v, int id,
                  int L0, int L1, int L2, int wv){
        float seed = fsigmoid(z5v);
        if (L2 == 0) bacc += seed*seed;
        int tc = 0, best = L0;
        if (L1 > best){ tc = 1; best = L1; }
        if (L2 > best){ tc = 2; }
        float m = fmaxf(z3v, fmaxf(z4v, z5v));
        float e3 = __expf(z3v-m), e4 = __expf(z4v-m), e5 = __expf(z5v-m);
        float sum = e3+e4+e5;
        float lse = m + __logf(sum);
        float zt = (tc==0) ? z3v : ((tc==1) ? z4v : z5v);
        float et = (tc==0) ? e3  : ((tc==1) ? e4  : e5);
        float lp = zt - lse;
        float pt = et*__builtin_amdgcn_rcpf(sum);
        float om = 1.0f - pt;
        facc -= om*om*lp;
        if (id > 0){
            atomicAdd(&s64[id-1],
                      (1ull<<42) | ((uint64)(uint32)wv<<21) | (uint64)(uint32)h0);
            atomicAdd(&ssig[id-1], sgv);
            atomicAdd(&ssig2[id-1], sgv*sgv);
        }
    };
    px(sg4.x, z3.x, z4.x, z5.x, id4.x, l0.x, l1.x, l2.x, w0);
    px(sg4.y, z3.y, z4.y, z5.y, id4.y, l0.y, l1.y, l2.y, w0+1);
    px(sg4.z, z3.z, z4.z, z5.z, id4.z, l0.z, l1.z, l2.z, w0+2);
    px(sg4.w, z3.w, z4.w, z5.w, id4.w, l0.w, l1.w, l2.w, w0+3);

    for (int o = 32; o; o >>= 1){
        facc += __shfl_xor(facc, o);
        bacc += __shfl_xor(bacc, o);
    }
    if ((t & 63) == 0){ wfb[t>>6][0] = facc; wfb[t>>6][1] = bacc; }
    __syncthreads();
    if (t < NID){
        pstat64[blk*16 + t] = s64[t];
        pstatf [blk*16 + t] = ssig[t];
        pstatf2[blk*16 + t] = ssig2[t];
    }
    if (t == 0){
        focal_p[blk]  = wfb[0][0]+wfb[1][0]+wfb[2][0]+wfb[3][0];
        bgseed_p[blk] = wfb[0][1]+wfb[1][1]+wfb[2][1]+wfb[3][1];
    }
}

// ---- phaseR: reduce partials -> stats, derived, var_sum; zero final hist ----
__global__ __launch_bounds__(512) void phaseR(const uint64* __restrict__ pstat64,
        const float* __restrict__ pstatf, const float* __restrict__ pstatf2,
        const float* __restrict__ focal_p, const float* __restrict__ bgseed_p,
        float* __restrict__ stats, float* __restrict__ derived,
        float* __restrict__ results,
        float* __restrict__ focalR, float* __restrict__ bgseedR,
        uint32* __restrict__ Hzero, float* __restrict__ part2f){
    int b = blockIdx.x;              // 8 blocks
    int t = threadIdx.x;
    {
        const int stripe = 2*NSEG*NBINS/8;
        for (int i = b*stripe + t; i < (b+1)*stripe; i += 512) Hzero[i] = 0u;
        if (b == 0 && t < NSEG) part2f[t] = 0.0f;
    }
    int k = t & 15, chunk = t >> 4;
    float acnt = 0, asw = 0, ash = 0, af = 0, af2 = 0;
    for (int i = 0; i < 8; i++){
        int blk = b*256 + chunk*8 + i;
        uint64 v = pstat64[blk*16 + k];
        acnt += (float)(uint32)(v >> 42);
        asw  += (float)(uint32)((v >> 21) & 0x1FFFFF);
        ash  += (float)(uint32)(v & 0x1FFFFF);
        af   += pstatf[blk*16 + k];
        af2  += pstatf2[blk*16 + k];
    }
    __shared__ float tc[16], tw[16], th[16], ts[16], ts2[16];
    if (t < 16){ tc[t]=0; tw[t]=0; th[t]=0; ts[t]=0; ts2[t]=0; }
    __syncthreads();
    atomicAdd(&tc[k], acnt);
    atomicAdd(&tw[k], asw);
    atomicAdd(&th[k], ash);
    atomicAdd(&ts[k], af);
    atomicAdd(&ts2[k], af2);
    __syncthreads();
    if (t < NID){
        float cnt = tc[t];
        float safe = fmaxf(cnt, 1.0f);
        float inv = 1.0f/safe;
        const float SC = 2.0f/511.0f;
        derived[(b*NID+t)*4+0] = tw[t]*SC*inv;
        derived[(b*NID+t)*4+1] = th[t]*SC*inv;
        float sm = ts[t]*inv;
        derived[(b*NID+t)*4+2] = __expf(10.0f*sm);
        derived[(b*NID+t)*4+3] = sm;
        stats[b*60 + t*4] = cnt;
        results[(size_t)(b*NID+t)*3 + 1] = ts2[t] - cnt*sm*sm;
    }
    int w = t >> 6, lane = t & 63;
    if (w == 0){
        float f = 0;
        for (int j = 0; j < 4; j++) f += focal_p[b*256 + j*64 + lane];
        for (int o = 32; o; o >>= 1) f += __shfl_xor(f, o);
        if (lane == 0) focalR[b] = f;
    } else if (w == 1){
        float g = 0;
        for (int j = 0; j < 4; j++) g += bgseed_p[b*256 + j*64 + lane];
        for (int o = 32; o; o >>= 1) g += __shfl_xor(g, o);
        if (lane == 0) bgseedR[b] = g;
    }
}

// ---- phaseLH: branchless bg loop (skip bin<1); captured-bin undo; fg fixup ----
__global__ __launch_bounds__(512, 8) void phaseLH(const float* __restrict__ pred,
        const int* __restrict__ inst, const float* __restrict__ derived,
        uint32* __restrict__ Hc, uint32* __restrict__ Hg,
        float* __restrict__ part2f){
    int idx = blockIdx.x;
    int b = idx & 7;                 // XCD affinity
    int sp = idx >> 3;
    int t = threadIdx.x;

    __shared__ __align__(16) uint32 hist[NID*NBINS];   // (count<<16)|fg, 15 KB
    __shared__ float ssl[NID];
    __shared__ float vsB[NID];
    {
        uint4* hz = (uint4*)hist;
        for (int i = t; i < NID*NBINS/4; i += 512) hz[i] = make_uint4(0,0,0,0);
    }
    if (t < NID){
        ssl[t] = derived[(size_t)(b*NID + t)*4 + 2];
        vsB[t] = 0.0f;
    }
    float kcx[NID], kcy[NID], kcs[NID];
    #pragma unroll
    for (int j = 0; j < NID; j++){
        const float* d0 = derived + (size_t)(b*NID + j)*4;
        kcx[j] = sconst(d0[0]);
        kcy[j] = sconst(d0[1]);
        kcs[j] = sconst(LOG2E*AAF*d0[2]);
    }
    __syncthreads();

    const int Q = HWH/4;
    const int qps = Q / SLICES;      // 512
    int q0 = sp * qps;
    const float* pb = pred + (size_t)b*6*HWH;
    const float4* P0 = (const float4*)pb;
    const float4* P1 = P0 + Q;
    const float* z5p = pb + 5*HWH;
    const int4* I = (const int4*)(inst + (size_t)b*HWH);
    const float SC = 2.0f/511.0f;

    for (int q = q0 + t; q < q0 + qps; q += 512){
        int4 id4 = I[q];
        float4 a = P0[q], c = P1[q];
        int p = q*4;
        float gx = (float)(p & 511)*SC;
        float gy = (float)(p >> 9)*SC;
        auto px = [&](float av, float cv, int id, float gxv, int pi){
            float ex = ftanh(av) + gxv;
            float ey = ftanh(cv) + gy;
            int own = id - 1;
            float r2own = 0.0f, binf_own = 0.0f;
            // branchless bg pass over all 15 ids; bin-0 hits skipped (derived in LS)
            #pragma unroll
            for (int j = 0; j < NID; j++){
                float dx = ex - kcx[j], dy = ey - kcy[j];
                float r2 = fmaf(dx, dx, dy*dy);
                float binf = fmaf(-kcs[j], r2, (float)NBINS);
                binf = fminf(binf, (float)(NBINS-1));
                if (j == own){ r2own = r2; binf_own = binf; }   // cndmask captures
                if (binf >= 1.0f)
                    atomicAdd(&hist[j*NBINS + (int)binf], 65536u);
            }
            if (own >= 0){
                if (binf_own >= 1.0f)              // undo EXACTLY the inserted bin
                    atomicAdd(&hist[own*NBINS + (int)binf_own], 0xFFFF0000u);
                float s = ssl[own];
                float d = __expf(-s*r2own);
                float e = fmaf(-2.0f, d, 2.0f);
                float bf = fmaf(__log2f(e), AAF, (float)NBINS - AAF);
                bf = fminf(fmaxf(bf, 0.0f), (float)(NBINS-1));
                atomicAdd(&hist[own*NBINS + (int)bf], 65537u);   // fg entry
                float seed = fsigmoid(z5p[pi]);
                float sd = seed - d;
                atomicAdd(&vsB[own], sd*sd);
            }
        };
        px(a.x, c.x, id4.x, gx,      p);
        px(a.y, c.y, id4.y, gx+SC,   p+1);
        px(a.z, c.z, id4.z, gx+2*SC, p+2);
        px(a.w, c.w, id4.w, gx+3*SC, p+3);
    }
    __syncthreads();
    // sparse atomic accumulation into the final per-segment histograms (L2-resident)
    size_t base = (size_t)b*NID*NBINS;
    for (int i = t; i < NID*NBINS; i += 512){
        uint32 v = hist[i];
        if (v){
            uint32 cc = v >> 16, gg = v & 0xFFFFu;
            if (cc) atomicAdd(&Hc[base + i], cc);
            if (gg) atomicAdd(&Hg[base + i], gg);
        }
    }
    if (t < NID && vsB[t] != 0.0f)
        atomicAdd(&part2f[b*NID + t], vsB[t]);
}

// ---- phaseLS: descending Lovasz scan with derived bin-0 ----
__global__ __launch_bounds__(256) void phaseLS(const uint32* __restrict__ Hc,
        const uint32* __restrict__ Hg, const float* __restrict__ part2f,
        const float* __restrict__ stats, float* __restrict__ results){
    int idx = blockIdx.x;            // 120
    int b = idx & 7, k = idx >> 3;
    int seg = b*NID + k;
    int t = threadIdx.x;             // 256

    __shared__ uint32 wbc[4], wbg[4], wexc[4], wexg[4];
    __shared__ float wsum[4];

    size_t base = (size_t)seg*NBINS;
    uint32 cd = Hc[base + NBINS-1-t];       // thread t handles bin NBINS-1-t
    uint32 gd = Hg[base + NBINS-1-t];
    uint32 ci = cd, gi2 = gd;
    int lane = t & 63, w = t >> 6;
    for (int o = 1; o < 64; o <<= 1){
        uint32 cu = __shfl_up(ci, o);
        uint32 gu = __shfl_up(gi2, o);
        if (lane >= o){ ci += cu; gi2 += gu; }
    }
    if (lane == 63){ wbc[w] = ci; wbg[w] = gi2; }
    __syncthreads();
    if (t == 0){
        uint32 rc = 0, rg = 0;
        for (int i = 0; i < 4; i++){
            uint32 a = wbc[i], bq = wbg[i];
            wexc[i] = rc; wexg[i] = rg;
            rc += a; rg += bq;
        }
    }
    __syncthreads();

    float G = stats[b*60 + k*4];
    // bin-0 bg inserts were skipped in phaseLH: derive so totals reach HWH
    uint32 cd_use = cd;
    if (t == NBINS-1){
        uint32 totalRaw = wexc[3] + wbc[3];
        cd_use = cd + ((uint32)HWH - totalRaw);
    }
    float contrib = 0.0f;
    if (G > 0.0f && (cd_use | gd)){
        uint32 nb = wexc[w] + (ci - cd);
        uint32 gb = wexg[w] + (gi2 - gd);
        float jp = 0.0f;
        if (nb > 0) jp = 1.0f - (G - (float)gb)/(G + (float)(nb - gb));
        uint32 n = nb + cd_use, gg = gb + gd;
        float j2 = 1.0f - (G - (float)gg)/(G + (float)(n - gg));
        int bin = NBINS-1-t;
        float ev = __expf(LN2*(((float)bin + 0.5f)*(13.0f/(float)NBINS) - 12.0f));
        contrib = ev*(j2 - jp);
    }
    for (int o = 32; o; o >>= 1) contrib += __shfl_xor(contrib, o);
    if (lane == 0) wsum[w] = contrib;
    __syncthreads();
    if (t == 0){
        results[(size_t)seg*3 + 0] = wsum[0]+wsum[1]+wsum[2]+wsum[3];
        results[(size_t)seg*3 + 2] = part2f[seg];
    }
}

// ---------------- phase5: final combine ----------------
__global__ void phase5(const float* __restrict__ stats, const float* __restrict__ results,
                       const float* __restrict__ bgseedR, const float* __restrict__ focalR,
                       float* __restrict__ out){
    int t = threadIdx.x;
    __shared__ float per_b[BB];
    if (t < BB){
        float nvalid = 0.0f, lsum = 0.0f, vsum = 0.0f, ssum = 0.0f;
        for (int k = 0; k < NID; k++){
            int seg = t*NID + k;
            float cnt = stats[t*60 + k*4];
            if (cnt > 0.0f){
                nvalid += 1.0f;
                lsum += results[(size_t)seg*3+0];
                vsum += results[(size_t)seg*3+1]/cnt;
                ssum += results[(size_t)seg*3+2];
            }
        }
        float nobj = fmaxf(nvalid, 1.0f);
        per_b[t] = lsum/nobj + 10.0f*(vsum/nobj) + (bgseedR[t] + ssum)/(float)HWH;
    }
    __syncthreads();
    if (t == 0){
        float s = 0.0f, fs = 0.0f;
        for (int b = 0; b < BB; b++){ s += per_b[b]; fs += focalR[b]; }
        out[0] = s/(float)BB + fs/(float)(BB*HWH);
    }
}

extern "C" void kernel_launch(void* const* d_in, const int* in_sizes, int n_in,
                              void* d_out, int out_size, void* d_ws, size_t ws_size,
                              hipStream_t stream){
    const float* pred  = (const float*)d_in[0];
    const int*   labels= (const int*)d_in[1];
    const int*   inst  = (const int*)d_in[2];
    float* out = (float*)d_out;

    uint32* Hc     = (uint32*)d_ws;                          // NSEG*NBINS
    uint32* Hg     = Hc + (size_t)NSEG*NBINS;                // NSEG*NBINS
    float* part2f  = (float*)(Hg + (size_t)NSEG*NBINS);      // NSEG (pad 128)
    uint64* pstat64= (uint64*)(part2f + 128);                // 2048*16
    float* pstatf  = (float*)(pstat64 + 2048*16);
    float* pstatf2 = pstatf + 2048*16;
    float* focal_p = pstatf2 + 2048*16;
    float* bgseed_p= focal_p + 2048;
    float* stats   = bgseed_p + 2048;
    float* derived = stats + 480;
    float* results = derived + 480;
    float* focalR  = results + 360;
    float* bgseedR = focalR + 8;

    hipLaunchKernelGGL(phase1f, dim3(2048), dim3(256), 0, stream,
                       pred, labels, inst, pstat64, pstatf, pstatf2,
                       bgseed_p, focal_p);
    hipLaunchKernelGGL(phaseR, dim3(8), dim3(512), 0, stream,
                       pstat64, pstatf, pstatf2, focal_p, bgseed_p,
                       stats, derived, results, focalR, bgseedR, Hc, part2f);
    hipLaunchKernelGGL(phaseLH, dim3(BB*SLICES), dim3(512), 0, stream,
                       pred, inst, derived, Hc, Hg, part2f);
    hipLaunchKernelGGL(phaseLS, dim3(NSEG), dim3(256), 0, stream,
                       Hc, Hg, part2f, stats, results);
    hipLaunchKernelGGL(phase5, dim3(1), dim3(64), 0, stream,
                       stats, results, bgseedR, focalR, out);
}

// Round 14
// 75.138 us; speedup vs baseline: 3.8470x; 1.0411x over previous
//
#include <hip/hip_runtime.h>
#include <math.h>

#define BB 8
#define HWH (512*512)
#define NID 15
#define NSEG (BB*NID)
#define NBINS 256
#define AAF ((float)NBINS/13.0f)
#define LOG2E 1.442695041f
#define LN2 0.6931471806f
#define SLICES 128

typedef unsigned int uint32;
typedef unsigned long long uint64;

__device__ __forceinline__ float ftanh(float x){
    float t = __expf(2.0f*x);
    return 1.0f - 2.0f*__builtin_amdgcn_rcpf(t + 1.0f);
}
__device__ __forceinline__ float fsigmoid(float x){
    return __builtin_amdgcn_rcpf(1.0f + __expf(-x));
}
__device__ __forceinline__ float sconst(float x){
    return __uint_as_float(__builtin_amdgcn_readfirstlane(__float_as_uint(x)));
}

// ---- phase1f: per-chunk id-stats + focal/bgseed; zero hist/out/part2f ----
__global__ __launch_bounds__(256, 8) void phase1f(const float* __restrict__ pred,
        const int* __restrict__ labels, const int* __restrict__ inst,
        uint64* __restrict__ pstat64, float* __restrict__ pstatf,
        float* __restrict__ pstatf2,
        float* __restrict__ bgseed_p, float* __restrict__ focal_p,
        uint32* __restrict__ Hzero, float* __restrict__ part2f,
        float* __restrict__ out){
    int blk = blockIdx.x;            // 2048 blocks, 256 per image
    int b = blk >> 8;
    int t = threadIdx.x;
    int q = (blk & 255)*256 + t;     // float4 index in image

    // distributed zeroing of the final histograms (2*NSEG*NBINS = 2048*30 words)
    if (t < 30) Hzero[blk*30 + t] = 0u;
    if (blk == 0 && t == 30) out[0] = 0.0f;
    if (blk == 1 && t < NSEG) part2f[t] = 0.0f;

    __shared__ uint64 s64[NID];
    __shared__ float ssig[NID], ssig2[NID];
    __shared__ float wfb[4][2];
    if (t < NID){ s64[t] = 0ull; ssig[t] = 0.0f; ssig2[t] = 0.0f; }
    __syncthreads();

    const int Q = HWH/4;
    const float4* P = (const float4*)(pred + (size_t)b*6*HWH);
    const int4* L = (const int4*)(labels + (size_t)b*3*HWH);
    const int4* I = (const int4*)(inst + (size_t)b*HWH);
    float4 sg4 = P[2*Q+q], z3 = P[3*Q+q], z4 = P[4*Q+q], z5 = P[5*Q+q];
    int4 id4 = I[q];
    int4 l0 = L[q], l1 = L[Q+q], l2 = L[2*Q+q];
    int p = q*4;
    int w0 = p & 511, h0 = p >> 9;

    float facc = 0.0f, bacc = 0.0f;
    auto px = [&](float sgv, float z3v, float z4v, float z5v, int id,
                  int L0, int L1, int L2, int wv){
        float seed = fsigmoid(z5v);
        if (L2 == 0) bacc += seed*seed;
        int tc = 0, best = L0;
        if (L1 > best){ tc = 1; best = L1; }
        if (L2 > best){ tc = 2; }
        float m = fmaxf(z3v, fmaxf(z4v, z5v));
        float e3 = __expf(z3v-m), e4 = __expf(z4v-m), e5 = __expf(z5v-m);
        float sum = e3+e4+e5;
        float lse = m + __logf(sum);
        float zt = (tc==0) ? z3v : ((tc==1) ? z4v : z5v);
        float et = (tc==0) ? e3  : ((tc==1) ? e4  : e5);
        float lp = zt - lse;
        float pt = et*__builtin_amdgcn_rcpf(sum);
        float om = 1.0f - pt;
        facc -= om*om*lp;
        if (id > 0){
            atomicAdd(&s64[id-1],
                      (1ull<<42) | ((uint64)(uint32)wv<<21) | (uint64)(uint32)h0);
            atomicAdd(&ssig[id-1], sgv);
            atomicAdd(&ssig2[id-1], sgv*sgv);
        }
    };
    px(sg4.x, z3.x, z4.x, z5.x, id4.x, l0.x, l1.x, l2.x, w0);
    px(sg4.y, z3.y, z4.y, z5.y, id4.y, l0.y, l1.y, l2.y, w0+1);
    px(sg4.z, z3.z, z4.z, z5.z, id4.z, l0.z, l1.z, l2.z, w0+2);
    px(sg4.w, z3.w, z4.w, z5.w, id4.w, l0.w, l1.w, l2.w, w0+3);

    for (int o = 32; o; o >>= 1){
        facc += __shfl_xor(facc, o);
        bacc += __shfl_xor(bacc, o);
    }
    if ((t & 63) == 0){ wfb[t>>6][0] = facc; wfb[t>>6][1] = bacc; }
    __syncthreads();
    if (t < NID){
        pstat64[blk*16 + t] = s64[t];
        pstatf [blk*16 + t] = ssig[t];
        pstatf2[blk*16 + t] = ssig2[t];
    }
    if (t == 0){
        focal_p[blk]  = wfb[0][0]+wfb[1][0]+wfb[2][0]+wfb[3][0];
        bgseed_p[blk] = wfb[0][1]+wfb[1][1]+wfb[2][1]+wfb[3][1];
    }
}

// ---- phaseR: reduce partials -> stats, derived, var_sum, nobj; focal/bgseed -> out ----
__global__ __launch_bounds__(512) void phaseR(const uint64* __restrict__ pstat64,
        const float* __restrict__ pstatf, const float* __restrict__ pstatf2,
        const float* __restrict__ focal_p, const float* __restrict__ bgseed_p,
        float* __restrict__ stats, float* __restrict__ derived,
        float* __restrict__ results, float* __restrict__ nobjR,
        float* __restrict__ out){
    int b = blockIdx.x;              // 8 blocks
    int t = threadIdx.x;
    int k = t & 15, chunk = t >> 4;  // 32 chunks x 8 partial-blocks
    float acnt = 0, asw = 0, ash = 0, af = 0, af2 = 0;
    for (int i = 0; i < 8; i++){
        int blk = b*256 + chunk*8 + i;
        uint64 v = pstat64[blk*16 + k];
        acnt += (float)(uint32)(v >> 42);
        asw  += (float)(uint32)((v >> 21) & 0x1FFFFF);
        ash  += (float)(uint32)(v & 0x1FFFFF);
        af   += pstatf[blk*16 + k];
        af2  += pstatf2[blk*16 + k];
    }
    __shared__ float tc[16], tw[16], th[16], ts[16], ts2[16];
    if (t < 16){ tc[t]=0; tw[t]=0; th[t]=0; ts[t]=0; ts2[t]=0; }
    __syncthreads();
    atomicAdd(&tc[k], acnt);
    atomicAdd(&tw[k], asw);
    atomicAdd(&th[k], ash);
    atomicAdd(&ts[k], af);
    atomicAdd(&ts2[k], af2);
    __syncthreads();
    if (t < NID){
        float cnt = tc[t];
        float safe = fmaxf(cnt, 1.0f);
        float inv = 1.0f/safe;
        const float SC = 2.0f/511.0f;
        derived[(b*NID+t)*4+0] = tw[t]*SC*inv;
        derived[(b*NID+t)*4+1] = th[t]*SC*inv;
        float sm = ts[t]*inv;
        derived[(b*NID+t)*4+2] = __expf(10.0f*sm);
        derived[(b*NID+t)*4+3] = sm;
        stats[b*60 + t*4] = cnt;
        results[(size_t)(b*NID+t)*3 + 1] = ts2[t] - cnt*sm*sm;
    }
    if (t == NID){
        float nv = 0.0f;
        for (int j = 0; j < NID; j++) nv += (tc[j] > 0.0f) ? 1.0f : 0.0f;
        nobjR[b] = fmaxf(nv, 1.0f);
    }
    int w = t >> 6, lane = t & 63;
    if (w == 0){
        float f = 0;
        for (int j = 0; j < 4; j++) f += focal_p[b*256 + j*64 + lane];
        for (int o = 32; o; o >>= 1) f += __shfl_xor(f, o);
        if (lane == 0) atomicAdd(out, f/(float)(BB*HWH));
    } else if (w == 1){
        float g = 0;
        for (int j = 0; j < 4; j++) g += bgseed_p[b*256 + j*64 + lane];
        for (int o = 32; o; o >>= 1) g += __shfl_xor(g, o);
        if (lane == 0) atomicAdd(out, g/(float)(BB*HWH));
    }
}

// ---- phaseLH: lane-decorrelated pixels; branchless bg loop; captured-bin undo ----
__global__ __launch_bounds__(512, 8) void phaseLH(const float* __restrict__ pred,
        const int* __restrict__ inst, const float* __restrict__ derived,
        uint32* __restrict__ Hc, uint32* __restrict__ Hg,
        float* __restrict__ part2f){
    int idx = blockIdx.x;
    int b = idx & 7;                 // XCD affinity
    int sp = idx >> 3;
    int t = threadIdx.x;
    int lane = t & 63, w = t >> 6;

    __shared__ __align__(16) uint32 hist[NID*NBINS];   // (count<<16)|fg, 15 KB
    __shared__ float ssl[NID];
    __shared__ float vsB[NID];
    {
        uint4* hz = (uint4*)hist;
        for (int i = t; i < NID*NBINS/4; i += 512) hz[i] = make_uint4(0,0,0,0);
    }
    if (t < NID){
        ssl[t] = derived[(size_t)(b*NID + t)*4 + 2];
        vsB[t] = 0.0f;
    }
    float kcx[NID], kcy[NID], kcs[NID];
    #pragma unroll
    for (int j = 0; j < NID; j++){
        const float* d0 = derived + (size_t)(b*NID + j)*4;
        kcx[j] = sconst(d0[0]);
        kcy[j] = sconst(d0[1]);
        kcs[j] = sconst(LOG2E*AAF*d0[2]);
    }
    __syncthreads();

    const int Q = HWH/4;
    const int qps = Q / SLICES;      // 512 float4 per block
    int q0 = sp * qps;
    const float* pb = pred + (size_t)b*6*HWH;
    const float4* P0 = (const float4*)pb;
    const float4* P1 = P0 + Q;
    const float* z5p = pb + 5*HWH;
    const int4* I = (const int4*)(inst + (size_t)b*HWH);
    const float SC = 2.0f/511.0f;

    // lane-decorrelated assignment: adjacent lanes 2 float4s (8 px) apart
    int q = q0 + lane*2 + (w & 1) + (w >> 1)*128;
    {
        int4 id4 = I[q];
        float4 a = P0[q], c = P1[q];
        int p = q*4;
        float gx = (float)(p & 511)*SC;
        float gy = (float)(p >> 9)*SC;
        auto px = [&](float av, float cv, int id, float gxv, int pi){
            float ex = ftanh(av) + gxv;
            float ey = ftanh(cv) + gy;
            int own = id - 1;
            float r2own = 0.0f, binf_own = 0.0f;
            #pragma unroll
            for (int j = 0; j < NID; j++){
                float dx = ex - kcx[j], dy = ey - kcy[j];
                float r2 = fmaf(dx, dx, dy*dy);
                float binf = fmaf(-kcs[j], r2, (float)NBINS);
                binf = fminf(binf, (float)(NBINS-1));
                if (j == own){ r2own = r2; binf_own = binf; }   // cndmask captures
                if (binf >= 1.0f)
                    atomicAdd(&hist[j*NBINS + (int)binf], 65536u);
            }
            if (own >= 0){
                if (binf_own >= 1.0f)              // undo EXACTLY the inserted bin
                    atomicAdd(&hist[own*NBINS + (int)binf_own], 0xFFFF0000u);
                float s = ssl[own];
                float d = __expf(-s*r2own);
                float e = fmaf(-2.0f, d, 2.0f);
                float bf = fmaf(__log2f(e), AAF, (float)NBINS - AAF);
                bf = fminf(fmaxf(bf, 0.0f), (float)(NBINS-1));
                atomicAdd(&hist[own*NBINS + (int)bf], 65537u);   // fg entry
                float seed = fsigmoid(z5p[pi]);
                float sd = seed - d;
                atomicAdd(&vsB[own], sd*sd);
            }
        };
        px(a.x, c.x, id4.x, gx,      p);
        px(a.y, c.y, id4.y, gx+SC,   p+1);
        px(a.z, c.z, id4.z, gx+2*SC, p+2);
        px(a.w, c.w, id4.w, gx+3*SC, p+3);
    }
    __syncthreads();
    // sparse atomic accumulation into the final per-segment histograms (L2-resident)
    size_t base = (size_t)b*NID*NBINS;
    for (int i = t; i < NID*NBINS; i += 512){
        uint32 v = hist[i];
        if (v){
            uint32 cc = v >> 16, gg = v & 0xFFFFu;
            if (cc) atomicAdd(&Hc[base + i], cc);
            if (gg) atomicAdd(&Hg[base + i], gg);
        }
    }
    if (t < NID && vsB[t] != 0.0f)
        atomicAdd(&part2f[b*NID + t], vsB[t]);
}

// ---- phaseLS: descending Lovasz scan with derived bin-0; fused final combine ----
__global__ __launch_bounds__(256) void phaseLS(const uint32* __restrict__ Hc,
        const uint32* __restrict__ Hg, const float* __restrict__ part2f,
        const float* __restrict__ stats, const float* __restrict__ results,
        const float* __restrict__ nobjR, float* __restrict__ out){
    int idx = blockIdx.x;            // 120
    int b = idx & 7, k = idx >> 3;
    int seg = b*NID + k;
    int t = threadIdx.x;             // 256

    __shared__ uint32 wbc[4], wbg[4], wexc[4], wexg[4];
    __shared__ float wsum[4];

    size_t base = (size_t)seg*NBINS;
    uint32 cd = Hc[base + NBINS-1-t];       // thread t handles bin NBINS-1-t
    uint32 gd = Hg[base + NBINS-1-t];
    uint32 ci = cd, gi2 = gd;
    int lane = t & 63, w = t >> 6;
    for (int o = 1; o < 64; o <<= 1){
        uint32 cu = __shfl_up(ci, o);
        uint32 gu = __shfl_up(gi2, o);
        if (lane >= o){ ci += cu; gi2 += gu; }
    }
    if (lane == 63){ wbc[w] = ci; wbg[w] = gi2; }
    __syncthreads();
    if (t == 0){
        uint32 rc = 0, rg = 0;
        for (int i = 0; i < 4; i++){
            uint32 a = wbc[i], bq = wbg[i];
            wexc[i] = rc; wexg[i] = rg;
            rc += a; rg += bq;
        }
    }
    __syncthreads();

    float G = stats[b*60 + k*4];
    // bin-0 bg inserts were skipped in phaseLH: derive so totals reach HWH
    uint32 cd_use = cd;
    if (t == NBINS-1){
        uint32 totalRaw = wexc[3] + wbc[3];
        cd_use = cd + ((uint32)HWH - totalRaw);
    }
    float contrib = 0.0f;
    if (G > 0.0f && (cd_use | gd)){
        uint32 nb = wexc[w] + (ci - cd);
        uint32 gb = wexg[w] + (gi2 - gd);
        float jp = 0.0f;
        if (nb > 0) jp = 1.0f - (G - (float)gb)/(G + (float)(nb - gb));
        uint32 n = nb + cd_use, gg = gb + gd;
        float j2 = 1.0f - (G - (float)gg)/(G + (float)(n - gg));
        int bin = NBINS-1-t;
        float ev = __expf(LN2*(((float)bin + 0.5f)*(13.0f/(float)NBINS) - 12.0f));
        contrib = ev*(j2 - jp);
    }
    for (int o = 32; o; o >>= 1) contrib += __shfl_xor(contrib, o);
    if (lane == 0) wsum[w] = contrib;
    __syncthreads();
    if (t == 0 && G > 0.0f){
        float lov = wsum[0]+wsum[1]+wsum[2]+wsum[3];
        float nobj = nobjR[b];
        float var = results[(size_t)seg*3 + 1];
        float seedsum = part2f[seg];
        float val = (lov + 10.0f*var/G)/(nobj*(float)BB)
                  + seedsum/((float)HWH*(float)BB);
        atomicAdd(out, val);
    }
}

extern "C" void kernel_launch(void* const* d_in, const int* in_sizes, int n_in,
                              void* d_out, int out_size, void* d_ws, size_t ws_size,
                              hipStream_t stream){
    const float* pred  = (const float*)d_in[0];
    const int*   labels= (const int*)d_in[1];
    const int*   inst  = (const int*)d_in[2];
    float* out = (float*)d_out;

    uint32* Hc     = (uint32*)d_ws;                          // NSEG*NBINS
    uint32* Hg     = Hc + (size_t)NSEG*NBINS;                // NSEG*NBINS
    float* part2f  = (float*)(Hg + (size_t)NSEG*NBINS);      // NSEG (pad 128)
    uint64* pstat64= (uint64*)(part2f + 128);                // 2048*16
    float* pstatf  = (float*)(pstat64 + 2048*16);
    float* pstatf2 = pstatf + 2048*16;
    float* focal_p = pstatf2 + 2048*16;
    float* bgseed_p= focal_p + 2048;
    float* stats   = bgseed_p + 2048;
    float* derived = stats + 480;
    float* results = derived + 480;
    float* nobjR   = results + 360;

    hipLaunchKernelGGL(phase1f, dim3(2048), dim3(256), 0, stream,
                       pred, labels, inst, pstat64, pstatf, pstatf2,
                       bgseed_p, focal_p, Hc, part2f, out);
    hipLaunchKernelGGL(phaseR, dim3(8), dim3(512), 0, stream,
                       pstat64, pstatf, pstatf2, focal_p, bgseed_p,
                       stats, derived, results, nobjR, out);
    hipLaunchKernelGGL(phaseLH, dim3(BB*SLICES), dim3(512), 0, stream,
                       pred, inst, derived, Hc, Hg, part2f);
    hipLaunchKernelGGL(phaseLS, dim3(NSEG), dim3(256), 0, stream,
                       Hc, Hg, part2f, stats, results, nobjR, out);
}